// Round 2
// baseline (3451.706 us; speedup 1.0000x reference)
//
#include <hip/hip_runtime.h>

#define T_DIM 2048
#define B_DIM 32
#define D_DIM 128
#define H_DIM 512
#define L_DIM 6
#define C_DIM 10
#define BN_EPS 1e-5f

constexpr int TB = T_DIM * B_DIM;           // 65536 rows (t-major, then b)
constexpr size_t TBH = (size_t)TB * H_DIM;  // 33,554,432 floats = 128 MB

// ---------------------------------------------------------------------------
// Row-wise GEMM, safe for in-place use (src may equal dst):
//   dst[m, o] = sum_k src[m, k] * W[o, k] + bias[o],  o in [0, 512)
// Each block owns RM=32 rows; stages them fully in LDS (transposed) before
// any write, so overwriting src rows is safe. N fixed at 512.
// ---------------------------------------------------------------------------
#define RM 32
#define NB 128
#define BK2 8

template <int K>
__global__ __launch_bounds__(256) void gemm_rows(const float* src,
                                                 const float* __restrict__ W,
                                                 const float* __restrict__ bias,
                                                 float* dst) {
  __shared__ float As[K][RM + 4];       // K x 36 floats (73.7 KB @ K=512)
  __shared__ float Bs[BK2][NB + 4];     // 8 x 132 floats (4.2 KB)
  const int tid = threadIdx.x;
  const size_t row0 = (size_t)blockIdx.x * RM;
  constexpr int K4 = K / 4;

  // ---- phase 1: stage all RM rows of src into LDS (transposed) ----
  const float* srcBase = src + row0 * K;
  for (int f = tid; f < RM * K4; f += 256) {
    int r = f / K4;
    int c4 = f - r * K4;
    float4 v = *(const float4*)(srcBase + (size_t)r * K + c4 * 4);
    As[c4 * 4 + 0][r] = v.x;
    As[c4 * 4 + 1][r] = v.y;
    As[c4 * 4 + 2][r] = v.z;
    As[c4 * 4 + 3][r] = v.w;
  }
  __syncthreads();

  const int tx = tid & 31;   // 32 col groups of 4  -> 128 cols per chunk
  const int ty = tid >> 5;   // 8 row groups of 4   -> 32 rows

  for (int nb = 0; nb < H_DIM / NB; ++nb) {   // 4 column chunks
    float acc[4][4] = {};
    for (int k0 = 0; k0 < K; k0 += BK2) {
      __syncthreads();  // protect Bs from previous iteration's readers
      {
        int o = tid >> 1;        // 0..127
        int c4 = tid & 1;        // 0..1
        float4 wv =
            *(const float4*)(W + (size_t)(nb * NB + o) * K + k0 + c4 * 4);
        Bs[c4 * 4 + 0][o] = wv.x;
        Bs[c4 * 4 + 1][o] = wv.y;
        Bs[c4 * 4 + 2][o] = wv.z;
        Bs[c4 * 4 + 3][o] = wv.w;
      }
      __syncthreads();
#pragma unroll
      for (int kk = 0; kk < BK2; ++kk) {
        float4 a = *(const float4*)&As[k0 + kk][ty * 4];
        float4 b = *(const float4*)&Bs[kk][tx * 4];
        float aa[4] = {a.x, a.y, a.z, a.w};
        float bb[4] = {b.x, b.y, b.z, b.w};
#pragma unroll
        for (int i = 0; i < 4; ++i)
#pragma unroll
          for (int j = 0; j < 4; ++j) acc[i][j] += aa[i] * bb[j];
      }
    }
    // ---- epilogue for this column chunk ----
    const int col = nb * NB + tx * 4;
    float4 bv = *(const float4*)(bias + col);
    float bb[4] = {bv.x, bv.y, bv.z, bv.w};
#pragma unroll
    for (int i = 0; i < 4; ++i) {
      float4 o;
      o.x = acc[i][0] + bb[0];
      o.y = acc[i][1] + bb[1];
      o.z = acc[i][2] + bb[2];
      o.w = acc[i][3] + bb[3];
      *(float4*)(dst + (row0 + ty * 4 + i) * H_DIM + col) = o;
    }
  }
}

// ---------------------------------------------------------------------------
// IndRNN scan, in-place over z (z becomes s), accumulating per-channel
// sum / sumsq for BatchNorm. One thread per (b,h) column, 16-deep chunks
// for memory-level parallelism.
// ---------------------------------------------------------------------------
__global__ __launch_bounds__(256) void indrnn_scan(float* __restrict__ z,
                                                   const float* __restrict__ u,
                                                   float* __restrict__ stats) {
  const int gid = blockIdx.x * 256 + threadIdx.x;  // 0..16383
  const int h = gid & (H_DIM - 1);
  const float uu = u[h];
  float hh = 0.f, sum = 0.f, sumsq = 0.f;
  float* p = z + gid;
  constexpr int STRIDE = B_DIM * H_DIM;  // 16384
  constexpr int CH = 16;
  float v[CH];
  for (int t0 = 0; t0 < T_DIM; t0 += CH) {
#pragma unroll
    for (int c = 0; c < CH; ++c) v[c] = p[(size_t)(t0 + c) * STRIDE];
#pragma unroll
    for (int c = 0; c < CH; ++c) {
      hh = fmaxf(v[c] + uu * hh, 0.f);
      v[c] = hh;
      sum += hh;
      sumsq += hh * hh;
    }
#pragma unroll
    for (int c = 0; c < CH; ++c) p[(size_t)(t0 + c) * STRIDE] = v[c];
  }
  atomicAdd(&stats[h], sum);
  atomicAdd(&stats[H_DIM + h], sumsq);
}

__global__ __launch_bounds__(1024) void zero_stats(float* __restrict__ stats) {
  stats[threadIdx.x] = 0.f;  // 1024 threads == 2*H exactly
}

__global__ __launch_bounds__(64) void fill_sentinel(float* __restrict__ out,
                                                    int n) {
  for (int i = threadIdx.x; i < n; i += 64) out[i] = 1.0e6f;
}

// ---------------------------------------------------------------------------
// Fold BN of previous layer into next layer's weights:
//   a[i] = gamma[i]*rsqrt(var[i]+eps); c[i] = beta[i] - mean[i]*a[i]
//   Wf[o,i] = Wn[o,i]*a[i];  bf[o] = bn[o] + sum_i Wn[o,i]*c[i]
// ---------------------------------------------------------------------------
__global__ __launch_bounds__(256) void bn_fold(const float* __restrict__ stats,
                                               const float* __restrict__ gamma,
                                               const float* __restrict__ beta,
                                               const float* __restrict__ Wn,
                                               const float* __restrict__ bn,
                                               float* __restrict__ Wf,
                                               float* __restrict__ bf) {
  const int o = blockIdx.x;
  const int tid = threadIdx.x;
  constexpr float invTB = 1.f / (float)(T_DIM * B_DIM);
  float part = 0.f;
  for (int i = tid; i < H_DIM; i += 256) {
    float mean = stats[i] * invTB;
    float var = stats[H_DIM + i] * invTB - mean * mean;
    float a = gamma[i] * rsqrtf(var + BN_EPS);
    float c = beta[i] - mean * a;
    float w = Wn[(size_t)o * H_DIM + i];
    Wf[(size_t)o * H_DIM + i] = w * a;
    part += w * c;
  }
  __shared__ float red[256];
  red[tid] = part;
  __syncthreads();
  for (int s = 128; s > 0; s >>= 1) {
    if (tid < s) red[tid] += red[tid + s];
    __syncthreads();
  }
  if (tid == 0) bf[o] = bn[o] + red[0];
}

// ---------------------------------------------------------------------------
// Final: out[b,c] = sum_i (s5[T-1,b,i]*a5[i] + c5[i]) * Wout[c,i] + bout[c]
// ---------------------------------------------------------------------------
__global__ __launch_bounds__(64) void final_out(const float* __restrict__ s5,
                                                const float* __restrict__ stats,
                                                const float* __restrict__ gamma,
                                                const float* __restrict__ beta,
                                                const float* __restrict__ Wout,
                                                const float* __restrict__ bout,
                                                float* __restrict__ out) {
  const int b = blockIdx.x / C_DIM, cls = blockIdx.x % C_DIM;
  const int lane = threadIdx.x;
  constexpr float invTB = 1.f / (float)(T_DIM * B_DIM);
  const float* srow =
      s5 + (size_t)(T_DIM - 1) * B_DIM * H_DIM + (size_t)b * H_DIM;
  float part = 0.f;
  for (int i = lane; i < H_DIM; i += 64) {
    float mean = stats[i] * invTB;
    float var = stats[H_DIM + i] * invTB - mean * mean;
    float a = gamma[i] * rsqrtf(var + BN_EPS);
    float c = beta[i] - mean * a;
    part += (srow[i] * a + c) * Wout[(size_t)cls * H_DIM + i];
  }
#pragma unroll
  for (int off = 32; off > 0; off >>= 1) part += __shfl_down(part, off);
  if (lane == 0) out[b * C_DIM + cls] = part + bout[cls];
}

// ---------------------------------------------------------------------------
extern "C" void kernel_launch(void* const* d_in, const int* in_sizes, int n_in,
                              void* d_out, int out_size, void* d_ws,
                              size_t ws_size, hipStream_t stream) {
  const float* x     = (const float*)d_in[0];
  const float* W0    = (const float*)d_in[1];
  const float* b0    = (const float*)d_in[2];
  const float* Wh    = (const float*)d_in[3];
  const float* bh    = (const float*)d_in[4];
  const float* u     = (const float*)d_in[5];
  const float* gamma = (const float*)d_in[6];
  const float* beta  = (const float*)d_in[7];
  const float* Wout  = (const float*)d_in[8];
  const float* bout  = (const float*)d_in[9];
  float* out = (float*)d_out;

  const size_t need =
      (TBH + (size_t)H_DIM * H_DIM + H_DIM + 2 * H_DIM) * sizeof(float);
  if (ws_size < need) {
    // Workspace too small for the single-buffer pipeline: emit sentinel so
    // the bench reports absmax ~1e6 instead of a GPU memory fault.
    fill_sentinel<<<1, 64, 0, stream>>>(out, out_size);
    return;
  }

  float* ws    = (float*)d_ws;
  float* buf   = ws;                          // 128 MB activations
  float* Wf    = ws + TBH;                    // 1 MB folded weights
  float* bf    = Wf + (size_t)H_DIM * H_DIM;  // 2 KB folded bias
  float* stats = bf + H_DIM;                  // 4 KB (sum, sumsq)

  const int gemm_blocks = TB / RM;            // 2048
  const int scan_blocks = (B_DIM * H_DIM) / 256;

  // ---- layer 0: out-of-place x -> buf ----
  gemm_rows<D_DIM><<<gemm_blocks, 256, 0, stream>>>(x, W0, b0, buf);
  zero_stats<<<1, 1024, 0, stream>>>(stats);
  indrnn_scan<<<scan_blocks, 256, 0, stream>>>(buf, u, stats);

  // ---- layers 1..5: in-place buf -> buf ----
  for (int l = 1; l < L_DIM; ++l) {
    bn_fold<<<H_DIM, 256, 0, stream>>>(
        stats, gamma + (size_t)(l - 1) * H_DIM, beta + (size_t)(l - 1) * H_DIM,
        Wh + (size_t)(l - 1) * H_DIM * H_DIM, bh + (size_t)(l - 1) * H_DIM, Wf,
        bf);
    gemm_rows<H_DIM><<<gemm_blocks, 256, 0, stream>>>(buf, Wf, bf, buf);
    zero_stats<<<1, 1024, 0, stream>>>(stats);
    indrnn_scan<<<scan_blocks, 256, 0, stream>>>(buf, u + (size_t)l * H_DIM,
                                                 stats);
  }

  // ---- final projection (BN of layer 5 applied on the fly) ----
  final_out<<<B_DIM * C_DIM, 64, 0, stream>>>(
      buf, stats, gamma + 5 * (size_t)H_DIM, beta + 5 * (size_t)H_DIM, Wout,
      bout, out);
}

// Round 3
// 1996.472 us; speedup vs baseline: 1.7289x; 1.7289x over previous
//
#include <hip/hip_runtime.h>

#define T_DIM 2048
#define B_DIM 32
#define D_DIM 128
#define H_DIM 512
#define L_DIM 6
#define C_DIM 10
#define BN_EPS 1e-5f

constexpr int TB = T_DIM * B_DIM;           // 65536 rows (t-major, then b)
constexpr size_t TBH = (size_t)TB * H_DIM;  // 33,554,432 floats = 128 MB

typedef short s16x8 __attribute__((ext_vector_type(8)));
typedef float f32x16 __attribute__((ext_vector_type(16)));

// ---- bf16 split helpers (bit-level, RNE) ----
__device__ inline unsigned short f2bf(float f) {
  unsigned u = __float_as_uint(f);
  unsigned r = (u + 0x7FFFu + ((u >> 16) & 1u)) >> 16;
  return (unsigned short)r;
}
__device__ inline float bf2f(unsigned short b) {
  return __uint_as_float((unsigned)b << 16);
}

// ---------------------------------------------------------------------------
// Split-bf16 MFMA GEMM, in-place safe (src may equal dst):
//   dst[m,o] = sum_k src[m,k] * W[o,k] + bias[o],  N = 512 fixed.
// Block = 32 rows, 4 waves. Rows staged to LDS as hi/lo bf16 (XOR-swizzled),
// W read as prepared bf16 hi/lo fragments from global (L2-hot, 1 MB).
// 3-MFMA split: Ah*Wh + Al*Wh + Ah*Wl  (~2^-17 rel err).
// ---------------------------------------------------------------------------
template <int K>
__global__ __launch_bounds__(256) void gemm_mfma(
    const float* src, const unsigned short* __restrict__ Whi,
    const unsigned short* __restrict__ Wlo, const float* __restrict__ bias,
    float* dst) {
  __shared__ __align__(16) unsigned short Ah[32 * K];
  __shared__ __align__(16) unsigned short Al[32 * K];
  const int tid = threadIdx.x;
  const size_t row0 = (size_t)blockIdx.x * 32;

  // ---- phase 1: stage 32 rows, split-convert f32 -> bf16 hi/lo ----
  constexpr int CPR = K / 8;  // 8-elem chunks per row
  const float* srcBase = src + row0 * K;
  for (int c = tid; c < 32 * CPR; c += 256) {
    int r = c / CPR;
    int kc = c - r * CPR;
    const float* p = srcBase + (size_t)r * K + kc * 8;
    float4 v0 = *(const float4*)p;
    float4 v1 = *(const float4*)(p + 4);
    float vv[8] = {v0.x, v0.y, v0.z, v0.w, v1.x, v1.y, v1.z, v1.w};
    s16x8 hi, lo;
#pragma unroll
    for (int j = 0; j < 8; ++j) {
      unsigned short h = f2bf(vv[j]);
      hi[j] = (short)h;
      lo[j] = (short)f2bf(vv[j] - bf2f(h));
    }
    int sc = kc ^ (r & 15);  // bank-conflict swizzle (16B granules)
    *(s16x8*)&Ah[r * K + sc * 8] = hi;
    *(s16x8*)&Al[r * K + sc * 8] = lo;
  }
  __syncthreads();

  const int lane = tid & 63;
  const int wave = tid >> 6;
  const int r31 = lane & 31;
  const int kg = lane >> 5;

  int woff[4];
#pragma unroll
  for (int nf = 0; nf < 4; ++nf)
    woff[nf] = (wave * 128 + nf * 32 + r31) * K + kg * 8;

  f32x16 acc[4] = {};
#pragma unroll 2
  for (int k0 = 0; k0 < K; k0 += 16) {
    int chunk = (k0 >> 3) + kg;
    int aidx = r31 * K + ((chunk ^ (r31 & 15)) << 3);
    s16x8 ah = *(const s16x8*)&Ah[aidx];
    s16x8 al = *(const s16x8*)&Al[aidx];
#pragma unroll
    for (int nf = 0; nf < 4; ++nf) {
      s16x8 wh = *(const s16x8*)(Whi + woff[nf] + k0);
      s16x8 wl = *(const s16x8*)(Wlo + woff[nf] + k0);
      acc[nf] =
          __builtin_amdgcn_mfma_f32_32x32x16_bf16(ah, wh, acc[nf], 0, 0, 0);
      acc[nf] =
          __builtin_amdgcn_mfma_f32_32x32x16_bf16(al, wh, acc[nf], 0, 0, 0);
      acc[nf] =
          __builtin_amdgcn_mfma_f32_32x32x16_bf16(ah, wl, acc[nf], 0, 0, 0);
    }
  }

  // ---- epilogue: D layout col=lane&31, row=(r&3)+8*(r>>2)+4*kg ----
#pragma unroll
  for (int nf = 0; nf < 4; ++nf) {
    int o = wave * 128 + nf * 32 + r31;
    float bb = bias[o];
#pragma unroll
    for (int r = 0; r < 16; ++r) {
      int m = (r & 3) + 8 * (r >> 2) + 4 * kg;
      dst[(row0 + m) * H_DIM + o] = acc[nf][r] + bb;
    }
  }
}

// ---------------------------------------------------------------------------
// IndRNN scan, in-place (z -> s), accumulating per-channel sum/sumsq.
// ---------------------------------------------------------------------------
__global__ __launch_bounds__(256) void indrnn_scan(float* __restrict__ z,
                                                   const float* __restrict__ u,
                                                   float* __restrict__ stats) {
  const int gid = blockIdx.x * 256 + threadIdx.x;  // 0..16383
  const int h = gid & (H_DIM - 1);
  const float uu = u[h];
  float hh = 0.f, sum = 0.f, sumsq = 0.f;
  float* p = z + gid;
  constexpr int STRIDE = B_DIM * H_DIM;  // 16384
  constexpr int CH = 16;
  float v[CH];
  for (int t0 = 0; t0 < T_DIM; t0 += CH) {
#pragma unroll
    for (int c = 0; c < CH; ++c) v[c] = p[(size_t)(t0 + c) * STRIDE];
#pragma unroll
    for (int c = 0; c < CH; ++c) {
      hh = fmaxf(v[c] + uu * hh, 0.f);
      v[c] = hh;
      sum += hh;
      sumsq += hh * hh;
    }
#pragma unroll
    for (int c = 0; c < CH; ++c) p[(size_t)(t0 + c) * STRIDE] = v[c];
  }
  atomicAdd(&stats[h], sum);
  atomicAdd(&stats[H_DIM + h], sumsq);
}

__global__ __launch_bounds__(1024) void zero_stats(float* __restrict__ stats) {
  stats[threadIdx.x] = 0.f;  // 1024 == 2*H exactly
}

__global__ __launch_bounds__(64) void fill_sentinel(float* __restrict__ out,
                                                    int n) {
  for (int i = threadIdx.x; i < n; i += 64) out[i] = 1.0e6f;
}

// ---------------------------------------------------------------------------
// Convert a raw f32 weight matrix to bf16 hi/lo (layer 0).
// ---------------------------------------------------------------------------
__global__ __launch_bounds__(256) void convert_w(
    const float* __restrict__ W, int n, unsigned short* __restrict__ Whi,
    unsigned short* __restrict__ Wlo) {
  int i = blockIdx.x * 256 + threadIdx.x;
  if (i < n) {
    float v = W[i];
    unsigned short h = f2bf(v);
    Whi[i] = h;
    Wlo[i] = f2bf(v - bf2f(h));
  }
}

// ---------------------------------------------------------------------------
// Fold BN of previous layer into next layer's weights, emit bf16 hi/lo:
//   a[i] = gamma[i]*rsqrt(var[i]+eps); c[i] = beta[i] - mean[i]*a[i]
//   Wf[o,i] = Wn[o,i]*a[i] (split to hi/lo);  bf[o] = bn[o] + sum_i Wn[o,i]*c[i]
// ---------------------------------------------------------------------------
__global__ __launch_bounds__(256) void bn_fold(
    const float* __restrict__ stats, const float* __restrict__ gamma,
    const float* __restrict__ beta, const float* __restrict__ Wn,
    const float* __restrict__ bn, unsigned short* __restrict__ Whi,
    unsigned short* __restrict__ Wlo, float* __restrict__ bf) {
  const int o = blockIdx.x;
  const int tid = threadIdx.x;
  constexpr float invTB = 1.f / (float)(T_DIM * B_DIM);
  float part = 0.f;
  for (int i = tid; i < H_DIM; i += 256) {
    float mean = stats[i] * invTB;
    float var = stats[H_DIM + i] * invTB - mean * mean;
    float a = gamma[i] * rsqrtf(var + BN_EPS);
    float c = beta[i] - mean * a;
    float w = Wn[(size_t)o * H_DIM + i];
    float wf = w * a;
    unsigned short h = f2bf(wf);
    Whi[(size_t)o * H_DIM + i] = h;
    Wlo[(size_t)o * H_DIM + i] = f2bf(wf - bf2f(h));
    part += w * c;
  }
  __shared__ float red[256];
  red[tid] = part;
  __syncthreads();
  for (int s = 128; s > 0; s >>= 1) {
    if (tid < s) red[tid] += red[tid + s];
    __syncthreads();
  }
  if (tid == 0) bf[o] = bn[o] + red[0];
}

// ---------------------------------------------------------------------------
// Final: out[b,c] = sum_i (s5[T-1,b,i]*a5[i] + c5[i]) * Wout[c,i] + bout[c]
// ---------------------------------------------------------------------------
__global__ __launch_bounds__(64) void final_out(const float* __restrict__ s5,
                                                const float* __restrict__ stats,
                                                const float* __restrict__ gamma,
                                                const float* __restrict__ beta,
                                                const float* __restrict__ Wout,
                                                const float* __restrict__ bout,
                                                float* __restrict__ out) {
  const int b = blockIdx.x / C_DIM, cls = blockIdx.x % C_DIM;
  const int lane = threadIdx.x;
  constexpr float invTB = 1.f / (float)(T_DIM * B_DIM);
  const float* srow =
      s5 + (size_t)(T_DIM - 1) * B_DIM * H_DIM + (size_t)b * H_DIM;
  float part = 0.f;
  for (int i = lane; i < H_DIM; i += 64) {
    float mean = stats[i] * invTB;
    float var = stats[H_DIM + i] * invTB - mean * mean;
    float a = gamma[i] * rsqrtf(var + BN_EPS);
    float c = beta[i] - mean * a;
    part += (srow[i] * a + c) * Wout[(size_t)cls * H_DIM + i];
  }
#pragma unroll
  for (int off = 32; off > 0; off >>= 1) part += __shfl_down(part, off);
  if (lane == 0) out[b * C_DIM + cls] = part + bout[cls];
}

// ---------------------------------------------------------------------------
extern "C" void kernel_launch(void* const* d_in, const int* in_sizes, int n_in,
                              void* d_out, int out_size, void* d_ws,
                              size_t ws_size, hipStream_t stream) {
  const float* x     = (const float*)d_in[0];
  const float* W0    = (const float*)d_in[1];
  const float* b0    = (const float*)d_in[2];
  const float* Wh    = (const float*)d_in[3];
  const float* bh    = (const float*)d_in[4];
  const float* u     = (const float*)d_in[5];
  const float* gamma = (const float*)d_in[6];
  const float* beta  = (const float*)d_in[7];
  const float* Wout  = (const float*)d_in[8];
  const float* bout  = (const float*)d_in[9];
  float* out = (float*)d_out;

  const size_t need = TBH * sizeof(float) +
                      (size_t)H_DIM * H_DIM * 2 * sizeof(unsigned short) +
                      3 * H_DIM * sizeof(float);
  if (ws_size < need) {
    fill_sentinel<<<1, 64, 0, stream>>>(out, out_size);
    return;
  }

  float* ws = (float*)d_ws;
  float* buf = ws;                                     // 128 MB activations
  unsigned short* Whi = (unsigned short*)(ws + TBH);   // 512 KB
  unsigned short* Wlo = Whi + (size_t)H_DIM * H_DIM;   // 512 KB
  float* bf = (float*)(Wlo + (size_t)H_DIM * H_DIM);   // 2 KB
  float* stats = bf + H_DIM;                           // 4 KB

  const int gemm_blocks = TB / 32;  // 2048
  const int scan_blocks = (B_DIM * H_DIM) / 256;

  // ---- layer 0: x (K=128) -> buf ----
  convert_w<<<(H_DIM * D_DIM + 255) / 256, 256, 0, stream>>>(
      W0, H_DIM * D_DIM, Whi, Wlo);
  gemm_mfma<D_DIM><<<gemm_blocks, 256, 0, stream>>>(x, Whi, Wlo, b0, buf);
  zero_stats<<<1, 1024, 0, stream>>>(stats);
  indrnn_scan<<<scan_blocks, 256, 0, stream>>>(buf, u, stats);

  // ---- layers 1..5: in-place buf -> buf ----
  for (int l = 1; l < L_DIM; ++l) {
    bn_fold<<<H_DIM, 256, 0, stream>>>(
        stats, gamma + (size_t)(l - 1) * H_DIM, beta + (size_t)(l - 1) * H_DIM,
        Wh + (size_t)(l - 1) * H_DIM * H_DIM, bh + (size_t)(l - 1) * H_DIM,
        Whi, Wlo, bf);
    gemm_mfma<H_DIM><<<gemm_blocks, 256, 0, stream>>>(buf, Whi, Wlo, bf, buf);
    zero_stats<<<1, 1024, 0, stream>>>(stats);
    indrnn_scan<<<scan_blocks, 256, 0, stream>>>(buf, u + (size_t)l * H_DIM,
                                                 stats);
  }

  // ---- final projection (BN of layer 5 applied on the fly) ----
  final_out<<<B_DIM * C_DIM, 64, 0, stream>>>(
      buf, stats, gamma + 5 * (size_t)H_DIM, beta + 5 * (size_t)H_DIM, Wout,
      bout, out);
}

// Round 4
// 1180.145 us; speedup vs baseline: 2.9248x; 1.6917x over previous
//
#include <hip/hip_runtime.h>

#define T_DIM 2048
#define B_DIM 32
#define D_DIM 128
#define H_DIM 512
#define L_DIM 6
#define C_DIM 10
#define BN_EPS 1e-5f

constexpr int TB = T_DIM * B_DIM;           // 65536 rows (t-major, then b)
constexpr size_t TBH = (size_t)TB * H_DIM;  // 33,554,432 floats = 128 MB

typedef short s16x8 __attribute__((ext_vector_type(8)));
typedef float f32x16 __attribute__((ext_vector_type(16)));

// ---- bf16 split helpers (bit-level, RNE) ----
__device__ inline unsigned short f2bf(float f) {
  unsigned u = __float_as_uint(f);
  unsigned r = (u + 0x7FFFu + ((u >> 16) & 1u)) >> 16;
  return (unsigned short)r;
}
__device__ inline float bf2f(unsigned short b) {
  return __uint_as_float((unsigned)b << 16);
}

// ---------------------------------------------------------------------------
// Split-bf16 MFMA GEMM, in-place safe (src may equal dst):
//   dst[m,o] = sum_k src[m,k] * W[o,k] + bias[o],  N = 512 fixed.
// 64 rows/block, 1024 threads (16 waves). Wave w owns output cols
// [w*32, w*32+32) x 64 rows (2 row-fragments). A staged in K-chunks of 128
// (double-buffered LDS, async split: issue loads -> compute -> write), W
// read from global in pre-swizzled fragment order (coalesced 1KB/wave) with
// 2-stage register prefetch. 3-MFMA split: Ah*Wh + Al*Wh + Ah*Wl.
// W fragment layout: elem (o,k) at ((c32*NIT+it)*64 + kg*32 + r31)*8 + j
//   where c32=o>>5, r31=o&31, it=k>>4, kg=(k>>3)&1, j=k&7.
// ---------------------------------------------------------------------------
#define ROWS 64
#define BKC 128

template <int K>
__global__ __launch_bounds__(1024, 4) void gemm_mfma(
    const float* src, const unsigned short* __restrict__ Whi,
    const unsigned short* __restrict__ Wlo, const float* __restrict__ bias,
    float* dst) {
  constexpr int NC = K / BKC;    // 1 (K=128) or 4 (K=512)
  constexpr int NITC = BKC / 16; // 8 MFMA k-steps per chunk
  constexpr int NIT = K / 16;
  __shared__ __align__(16) unsigned short AhS[2][ROWS * BKC];  // 32 KB
  __shared__ __align__(16) unsigned short AlS[2][ROWS * BKC];  // 32 KB

  const int tid = threadIdx.x;
  const size_t row0 = (size_t)blockIdx.x * ROWS;
  const int lane = tid & 63;
  const int wave = tid >> 6;        // 0..15 == c32
  const int r31 = lane & 31;
  const int kg = lane >> 5;

  // staging identity: one 8-elem granule per thread per chunk
  const int sr = tid >> 4;          // row 0..63
  const int sk = tid & 15;          // granule 0..15 within chunk
  const float* sp = src + (row0 + sr) * K + sk * 8;
  const int ssc = (sk ^ (sr & 15)) << 3;  // swizzled LDS elem offset

  // W fragment base (coalesced: lane*8 contiguous)
  const unsigned short* pWh = Whi + ((size_t)wave * NIT * 64 + lane) * 8;
  const unsigned short* pWl = Wlo + ((size_t)wave * NIT * 64 + lane) * 8;

  float4 v0, v1;  // in-flight A granule
  // ---- prologue: stage chunk 0 ----
  v0 = *(const float4*)sp;
  v1 = *(const float4*)(sp + 4);
  {
    float vv[8] = {v0.x, v0.y, v0.z, v0.w, v1.x, v1.y, v1.z, v1.w};
    s16x8 hi, lo;
#pragma unroll
    for (int j = 0; j < 8; ++j) {
      unsigned short h = f2bf(vv[j]);
      hi[j] = (short)h;
      lo[j] = (short)f2bf(vv[j] - bf2f(h));
    }
    *(s16x8*)&AhS[0][sr * BKC + ssc] = hi;
    *(s16x8*)&AlS[0][sr * BKC + ssc] = lo;
  }
  // W pipeline prologue: fragment itg=0 into slot 0
  s16x8 wh[2], wl[2];
  wh[0] = *(const s16x8*)pWh;
  wl[0] = *(const s16x8*)pWl;
  __syncthreads();

  f32x16 acc[2] = {};
#pragma unroll
  for (int c = 0; c < NC; ++c) {
    // issue next chunk's global loads early (latency hides under MFMAs)
    if (c + 1 < NC) {
      v0 = *(const float4*)(sp + (c + 1) * BKC);
      v1 = *(const float4*)(sp + (c + 1) * BKC + 4);
    }
    const int b = c & 1;
#pragma unroll
    for (int it = 0; it < NITC; ++it) {
      const int itg = c * NITC + it;
      if (itg + 1 < NIT) {  // prefetch next W fragments
        wh[(it + 1) & 1] = *(const s16x8*)(pWh + (size_t)(itg + 1) * 512);
        wl[(it + 1) & 1] = *(const s16x8*)(pWl + (size_t)(itg + 1) * 512);
      }
      const int ch = ((it * 2 + kg) ^ (r31 & 15)) << 3;
      const int ch2 = ((it * 2 + kg) ^ ((r31 & 15) /*rows 32..63: same &15*/)) << 3;
      const int a0 = r31 * BKC + ch;
      const int a1 = (32 + r31) * BKC + ch2;
      s16x8 ah0 = *(const s16x8*)&AhS[b][a0];
      s16x8 al0 = *(const s16x8*)&AlS[b][a0];
      s16x8 ah1 = *(const s16x8*)&AhS[b][a1];
      s16x8 al1 = *(const s16x8*)&AlS[b][a1];
      const int ws = it & 1;
      acc[0] = __builtin_amdgcn_mfma_f32_32x32x16_bf16(ah0, wh[ws], acc[0], 0, 0, 0);
      acc[0] = __builtin_amdgcn_mfma_f32_32x32x16_bf16(al0, wh[ws], acc[0], 0, 0, 0);
      acc[0] = __builtin_amdgcn_mfma_f32_32x32x16_bf16(ah0, wl[ws], acc[0], 0, 0, 0);
      acc[1] = __builtin_amdgcn_mfma_f32_32x32x16_bf16(ah1, wh[ws], acc[1], 0, 0, 0);
      acc[1] = __builtin_amdgcn_mfma_f32_32x32x16_bf16(al1, wh[ws], acc[1], 0, 0, 0);
      acc[1] = __builtin_amdgcn_mfma_f32_32x32x16_bf16(ah1, wl[ws], acc[1], 0, 0, 0);
    }
    if (c + 1 < NC) {  // convert + write staged chunk
      float vv[8] = {v0.x, v0.y, v0.z, v0.w, v1.x, v1.y, v1.z, v1.w};
      s16x8 hi, lo;
#pragma unroll
      for (int j = 0; j < 8; ++j) {
        unsigned short h = f2bf(vv[j]);
        hi[j] = (short)h;
        lo[j] = (short)f2bf(vv[j] - bf2f(h));
      }
      const int nb = (c + 1) & 1;
      *(s16x8*)&AhS[nb][sr * BKC + ssc] = hi;
      *(s16x8*)&AlS[nb][sr * BKC + ssc] = lo;
      __syncthreads();
    }
  }

  // ---- epilogue: D layout col=lane&31, row=(r&3)+8*(r>>2)+4*kg ----
  const int o = wave * 32 + r31;
  const float bb = bias[o];
#pragma unroll
  for (int rb = 0; rb < 2; ++rb) {
#pragma unroll
    for (int r = 0; r < 16; ++r) {
      int m = rb * 32 + (r & 3) + 8 * (r >> 2) + 4 * kg;
      dst[(row0 + m) * H_DIM + o] = acc[rb][r] + bb;
    }
  }
}

// ---------------------------------------------------------------------------
// IndRNN scan, in-place (z -> s), accumulating per-channel sum/sumsq.
// 64-thread blocks so every CU gets a wave.
// ---------------------------------------------------------------------------
__global__ __launch_bounds__(64) void indrnn_scan(float* __restrict__ z,
                                                  const float* __restrict__ u,
                                                  float* __restrict__ stats) {
  const int gid = blockIdx.x * 64 + threadIdx.x;  // 0..16383
  const int h = gid & (H_DIM - 1);
  const float uu = u[h];
  float hh = 0.f, sum = 0.f, sumsq = 0.f;
  float* p = z + gid;
  constexpr int STRIDE = B_DIM * H_DIM;  // 16384
  constexpr int CH = 16;
  float v[CH];
  for (int t0 = 0; t0 < T_DIM; t0 += CH) {
#pragma unroll
    for (int c = 0; c < CH; ++c) v[c] = p[(size_t)(t0 + c) * STRIDE];
#pragma unroll
    for (int c = 0; c < CH; ++c) {
      hh = fmaxf(v[c] + uu * hh, 0.f);
      v[c] = hh;
      sum += hh;
      sumsq += hh * hh;
    }
#pragma unroll
    for (int c = 0; c < CH; ++c) p[(size_t)(t0 + c) * STRIDE] = v[c];
  }
  atomicAdd(&stats[h], sum);
  atomicAdd(&stats[H_DIM + h], sumsq);
}

__global__ __launch_bounds__(1024) void zero_stats(float* __restrict__ stats) {
  stats[threadIdx.x] = 0.f;  // 1024 == 2*H exactly
}

__global__ __launch_bounds__(64) void fill_sentinel(float* __restrict__ out,
                                                    int n) {
  for (int i = threadIdx.x; i < n; i += 64) out[i] = 1.0e6f;
}

// ---------------------------------------------------------------------------
// Convert raw f32 weights (layer 0) to bf16 hi/lo in fragment-swizzled order.
// ---------------------------------------------------------------------------
template <int K>
__global__ __launch_bounds__(256) void convert_w(
    const float* __restrict__ W, unsigned short* __restrict__ Whi,
    unsigned short* __restrict__ Wlo) {
  constexpr int NIT = K / 16;
  int i = blockIdx.x * 256 + threadIdx.x;
  if (i < H_DIM * K) {
    int o = i / K, k = i % K;
    float v = W[i];
    unsigned short h = f2bf(v);
    size_t idx =
        ((size_t)((o >> 5) * NIT + (k >> 4)) * 64 + ((k >> 3) & 1) * 32 +
         (o & 31)) * 8 + (k & 7);
    Whi[idx] = h;
    Wlo[idx] = f2bf(v - bf2f(h));
  }
}

// ---------------------------------------------------------------------------
// Fold BN of previous layer into next layer's weights, emit swizzled bf16:
//   a[i] = gamma[i]*rsqrt(var[i]+eps); c[i] = beta[i] - mean[i]*a[i]
//   Wf[o,i] = Wn[o,i]*a[i];  bf[o] = bn[o] + sum_i Wn[o,i]*c[i]
// ---------------------------------------------------------------------------
__global__ __launch_bounds__(256) void bn_fold(
    const float* __restrict__ stats, const float* __restrict__ gamma,
    const float* __restrict__ beta, const float* __restrict__ Wn,
    const float* __restrict__ bn, unsigned short* __restrict__ Whi,
    unsigned short* __restrict__ Wlo, float* __restrict__ bf) {
  constexpr int NIT = H_DIM / 16;
  const int o = blockIdx.x;
  const int tid = threadIdx.x;
  constexpr float invTB = 1.f / (float)(T_DIM * B_DIM);
  float part = 0.f;
  for (int i = tid; i < H_DIM; i += 256) {
    float mean = stats[i] * invTB;
    float var = stats[H_DIM + i] * invTB - mean * mean;
    float a = gamma[i] * rsqrtf(var + BN_EPS);
    float c = beta[i] - mean * a;
    float w = Wn[(size_t)o * H_DIM + i];
    float wf = w * a;
    unsigned short h = f2bf(wf);
    size_t idx =
        ((size_t)((o >> 5) * NIT + (i >> 4)) * 64 + ((i >> 3) & 1) * 32 +
         (o & 31)) * 8 + (i & 7);
    Whi[idx] = h;
    Wlo[idx] = f2bf(wf - bf2f(h));
    part += w * c;
  }
  __shared__ float red[256];
  red[tid] = part;
  __syncthreads();
  for (int s = 128; s > 0; s >>= 1) {
    if (tid < s) red[tid] += red[tid + s];
    __syncthreads();
  }
  if (tid == 0) bf[o] = bn[o] + red[0];
}

// ---------------------------------------------------------------------------
// Final: out[b,c] = sum_i (s5[T-1,b,i]*a5[i] + c5[i]) * Wout[c,i] + bout[c]
// ---------------------------------------------------------------------------
__global__ __launch_bounds__(64) void final_out(const float* __restrict__ s5,
                                                const float* __restrict__ stats,
                                                const float* __restrict__ gamma,
                                                const float* __restrict__ beta,
                                                const float* __restrict__ Wout,
                                                const float* __restrict__ bout,
                                                float* __restrict__ out) {
  const int b = blockIdx.x / C_DIM, cls = blockIdx.x % C_DIM;
  const int lane = threadIdx.x;
  constexpr float invTB = 1.f / (float)(T_DIM * B_DIM);
  const float* srow =
      s5 + (size_t)(T_DIM - 1) * B_DIM * H_DIM + (size_t)b * H_DIM;
  float part = 0.f;
  for (int i = lane; i < H_DIM; i += 64) {
    float mean = stats[i] * invTB;
    float var = stats[H_DIM + i] * invTB - mean * mean;
    float a = gamma[i] * rsqrtf(var + BN_EPS);
    float c = beta[i] - mean * a;
    part += (srow[i] * a + c) * Wout[(size_t)cls * H_DIM + i];
  }
#pragma unroll
  for (int off = 32; off > 0; off >>= 1) part += __shfl_down(part, off);
  if (lane == 0) out[b * C_DIM + cls] = part + bout[cls];
}

// ---------------------------------------------------------------------------
extern "C" void kernel_launch(void* const* d_in, const int* in_sizes, int n_in,
                              void* d_out, int out_size, void* d_ws,
                              size_t ws_size, hipStream_t stream) {
  const float* x     = (const float*)d_in[0];
  const float* W0    = (const float*)d_in[1];
  const float* b0    = (const float*)d_in[2];
  const float* Wh    = (const float*)d_in[3];
  const float* bh    = (const float*)d_in[4];
  const float* u     = (const float*)d_in[5];
  const float* gamma = (const float*)d_in[6];
  const float* beta  = (const float*)d_in[7];
  const float* Wout  = (const float*)d_in[8];
  const float* bout  = (const float*)d_in[9];
  float* out = (float*)d_out;

  const size_t need = TBH * sizeof(float) +
                      (size_t)H_DIM * H_DIM * 2 * sizeof(unsigned short) +
                      3 * H_DIM * sizeof(float);
  if (ws_size < need) {
    fill_sentinel<<<1, 64, 0, stream>>>(out, out_size);
    return;
  }

  float* ws = (float*)d_ws;
  float* buf = ws;                                     // 128 MB activations
  unsigned short* Whi = (unsigned short*)(ws + TBH);   // 512 KB
  unsigned short* Wlo = Whi + (size_t)H_DIM * H_DIM;   // 512 KB
  float* bf = (float*)(Wlo + (size_t)H_DIM * H_DIM);   // 2 KB
  float* stats = bf + H_DIM;                           // 4 KB

  const int gemm_blocks = TB / ROWS;  // 1024
  const int scan_blocks = (B_DIM * H_DIM) / 64;

  // ---- layer 0: x (K=128) -> buf ----
  convert_w<D_DIM><<<(H_DIM * D_DIM + 255) / 256, 256, 0, stream>>>(W0, Whi,
                                                                    Wlo);
  gemm_mfma<D_DIM><<<gemm_blocks, 1024, 0, stream>>>(x, Whi, Wlo, b0, buf);
  zero_stats<<<1, 1024, 0, stream>>>(stats);
  indrnn_scan<<<scan_blocks, 64, 0, stream>>>(buf, u, stats);

  // ---- layers 1..5: in-place buf -> buf ----
  for (int l = 1; l < L_DIM; ++l) {
    bn_fold<<<H_DIM, 256, 0, stream>>>(
        stats, gamma + (size_t)(l - 1) * H_DIM, beta + (size_t)(l - 1) * H_DIM,
        Wh + (size_t)(l - 1) * H_DIM * H_DIM, bh + (size_t)(l - 1) * H_DIM,
        Whi, Wlo, bf);
    gemm_mfma<H_DIM><<<gemm_blocks, 1024, 0, stream>>>(buf, Whi, Wlo, bf, buf);
    zero_stats<<<1, 1024, 0, stream>>>(stats);
    indrnn_scan<<<scan_blocks, 64, 0, stream>>>(buf, u + (size_t)l * H_DIM,
                                                stats);
  }

  // ---- final projection (BN of layer 5 applied on the fly) ----
  final_out<<<B_DIM * C_DIM, 64, 0, stream>>>(
      buf, stats, gamma + 5 * (size_t)H_DIM, beta + 5 * (size_t)H_DIM, Wout,
      bout, out);
}

// Round 5
// 967.847 us; speedup vs baseline: 3.5664x; 1.2194x over previous
//
#include <hip/hip_runtime.h>

#define T_DIM 2048
#define B_DIM 32
#define D_DIM 128
#define H_DIM 512
#define L_DIM 6
#define C_DIM 10
#define BN_EPS 1e-5f

constexpr int TB = T_DIM * B_DIM;           // 65536 rows (t-major, then b)
constexpr size_t TBH = (size_t)TB * H_DIM;  // 33,554,432 floats = 128 MB

typedef short s16x8 __attribute__((ext_vector_type(8)));
typedef float f32x16 __attribute__((ext_vector_type(16)));

// ---- bf16 split helpers (bit-level, RNE) ----
__device__ inline unsigned short f2bf(float f) {
  unsigned u = __float_as_uint(f);
  unsigned r = (u + 0x7FFFu + ((u >> 16) & 1u)) >> 16;
  return (unsigned short)r;
}
__device__ inline float bf2f(unsigned short b) {
  return __uint_as_float((unsigned)b << 16);
}

// ---------------------------------------------------------------------------
// Split-bf16 MFMA GEMM, in-place safe (src may equal dst):
//   dst[m,o] = sum_k src[m,k] * W[o,k] + bias[o],  N = 512 fixed.
// 64 rows/block, 512 threads (8 waves). Wave w owns 64 rows x 64 cols
// (2 row-frags x 2 col-frags -> 12 MFMA per K=16 step vs 4 LDS reads + 4 W
// loads: LDS & W pressure per MFMA halved vs rf2cf1). A staged in K-chunks
// of 128 (double-buffered LDS, async: issue loads -> compute -> write), W
// read from global in pre-swizzled fragment order (coalesced 1KB/wave-load)
// with ring-2 register prefetch. 3-MFMA split: Ah*Wh + Al*Wh + Ah*Wl.
// W fragment layout: elem (o,k) at ((c32*NIT+itg)*64 + kg*32 + r31)*8 + j
//   where c32=o>>5, r31=o&31, itg=k>>4, kg=(k>>3)&1, j=k&7.
// ---------------------------------------------------------------------------
#define ROWS 64
#define BKC 128

template <int K>
__global__ __launch_bounds__(512, 4) void gemm_mfma(
    const float* src, const unsigned short* __restrict__ Whi,
    const unsigned short* __restrict__ Wlo, const float* __restrict__ bias,
    float* dst) {
  constexpr int NC = K / BKC;     // 1 (K=128) or 4 (K=512)
  constexpr int NITC = BKC / 16;  // 8 MFMA k-steps per chunk
  constexpr int NIT = K / 16;
  __shared__ __align__(16) unsigned short AhS[2][ROWS * BKC];  // 32 KB
  __shared__ __align__(16) unsigned short AlS[2][ROWS * BKC];  // 32 KB

  const int tid = threadIdx.x;
  const size_t row0 = (size_t)blockIdx.x * ROWS;
  const int lane = tid & 63;
  const int wave = tid >> 6;  // 0..7 = col-group of 64
  const int r31 = lane & 31;
  const int kg = lane >> 5;

  // staging: two 8-elem granules per thread per chunk (g = tid, tid+512)
  const int sr0 = tid >> 4, sk0 = tid & 15;
  const int sr1 = (tid + 512) >> 4, sk1 = tid & 15;
  const float* sp0 = src + (row0 + sr0) * K + sk0 * 8;
  const float* sp1 = src + (row0 + sr1) * K + sk1 * 8;
  const int ss0 = sr0 * BKC + ((sk0 ^ (sr0 & 15)) << 3);
  const int ss1 = sr1 * BKC + ((sk1 ^ (sr1 & 15)) << 3);

  // W fragment bases for this wave's two col-frags (coalesced 16B/lane)
  const unsigned short* pWh0 = Whi + ((size_t)(wave * 2 + 0) * NIT * 64 + lane) * 8;
  const unsigned short* pWh1 = Whi + ((size_t)(wave * 2 + 1) * NIT * 64 + lane) * 8;
  const unsigned short* pWl0 = Wlo + ((size_t)(wave * 2 + 0) * NIT * 64 + lane) * 8;
  const unsigned short* pWl1 = Wlo + ((size_t)(wave * 2 + 1) * NIT * 64 + lane) * 8;

  auto cvt_store = [&](float4 a, float4 b, unsigned short* dh,
                       unsigned short* dl) {
    float vv[8] = {a.x, a.y, a.z, a.w, b.x, b.y, b.z, b.w};
    s16x8 hi, lo;
#pragma unroll
    for (int j = 0; j < 8; ++j) {
      unsigned short h = f2bf(vv[j]);
      hi[j] = (short)h;
      lo[j] = (short)f2bf(vv[j] - bf2f(h));
    }
    *(s16x8*)dh = hi;
    *(s16x8*)dl = lo;
  };

  // ---- prologue: stage chunk 0 ----
  {
    float4 a0 = *(const float4*)sp0, a1 = *(const float4*)(sp0 + 4);
    float4 b0 = *(const float4*)sp1, b1 = *(const float4*)(sp1 + 4);
    cvt_store(a0, a1, &AhS[0][ss0], &AlS[0][ss0]);
    cvt_store(b0, b1, &AhS[0][ss1], &AlS[0][ss1]);
  }
  // ---- W ring prologue: fragment itg=0 into slot 0 ----
  s16x8 whr[2][2], wlr[2][2];
  whr[0][0] = *(const s16x8*)pWh0;
  whr[0][1] = *(const s16x8*)pWh1;
  wlr[0][0] = *(const s16x8*)pWl0;
  wlr[0][1] = *(const s16x8*)pWl1;
  __syncthreads();

  f32x16 acc[2][2] = {};
  float4 a0, a1, b0, b1;  // in-flight next-chunk A
#pragma unroll
  for (int c = 0; c < NC; ++c) {
    if (c + 1 < NC) {  // issue next chunk's loads (hide under MFMAs)
      a0 = *(const float4*)(sp0 + (c + 1) * BKC);
      a1 = *(const float4*)(sp0 + (c + 1) * BKC + 4);
      b0 = *(const float4*)(sp1 + (c + 1) * BKC);
      b1 = *(const float4*)(sp1 + (c + 1) * BKC + 4);
    }
    const int bsel = c & 1;
#pragma unroll
    for (int it = 0; it < NITC; ++it) {
      const int itg = c * NITC + it;
      const int sl = it & 1, sn = (it + 1) & 1;
      if (itg + 1 < NIT) {  // ring-2 W prefetch
        whr[sn][0] = *(const s16x8*)(pWh0 + (size_t)(itg + 1) * 512);
        whr[sn][1] = *(const s16x8*)(pWh1 + (size_t)(itg + 1) * 512);
        wlr[sn][0] = *(const s16x8*)(pWl0 + (size_t)(itg + 1) * 512);
        wlr[sn][1] = *(const s16x8*)(pWl1 + (size_t)(itg + 1) * 512);
      }
      const int gi = it * 2 + kg;
#pragma unroll
      for (int rf = 0; rf < 2; ++rf) {
        const int row = rf * 32 + r31;
        const int aidx = row * BKC + ((gi ^ (row & 15)) << 3);
        s16x8 ah = *(const s16x8*)&AhS[bsel][aidx];
        s16x8 al = *(const s16x8*)&AlS[bsel][aidx];
#pragma unroll
        for (int cf = 0; cf < 2; ++cf) {
          acc[rf][cf] = __builtin_amdgcn_mfma_f32_32x32x16_bf16(
              ah, whr[sl][cf], acc[rf][cf], 0, 0, 0);
          acc[rf][cf] = __builtin_amdgcn_mfma_f32_32x32x16_bf16(
              al, whr[sl][cf], acc[rf][cf], 0, 0, 0);
          acc[rf][cf] = __builtin_amdgcn_mfma_f32_32x32x16_bf16(
              ah, wlr[sl][cf], acc[rf][cf], 0, 0, 0);
        }
      }
    }
    if (c + 1 < NC) {  // convert + write staged chunk, one barrier per chunk
      const int nb = (c + 1) & 1;
      cvt_store(a0, a1, &AhS[nb][ss0], &AlS[nb][ss0]);
      cvt_store(b0, b1, &AhS[nb][ss1], &AlS[nb][ss1]);
      __syncthreads();
    }
  }

  // ---- epilogue: D layout col=lane&31, row=(r&3)+8*(r>>2)+4*kg ----
#pragma unroll
  for (int cf = 0; cf < 2; ++cf) {
    const int o = wave * 64 + cf * 32 + r31;
    const float bb = bias[o];
#pragma unroll
    for (int rf = 0; rf < 2; ++rf) {
#pragma unroll
      for (int r = 0; r < 16; ++r) {
        int m = rf * 32 + (r & 3) + 8 * (r >> 2) + 4 * kg;
        dst[(row0 + m) * H_DIM + o] = acc[rf][cf][r] + bb;
      }
    }
  }
}

// ---------------------------------------------------------------------------
// IndRNN scan, in-place (z -> s), accumulating per-channel sum/sumsq.
// One thread per (b,h) chain; CH=32 chunks, register double-buffered
// (load chunk n+1 while computing chunk n). 64-thread blocks -> 1 wave/CU.
// ---------------------------------------------------------------------------
__global__ __launch_bounds__(64) void indrnn_scan(float* __restrict__ z,
                                                  const float* __restrict__ u,
                                                  float* __restrict__ stats) {
  const int gid = blockIdx.x * 64 + threadIdx.x;  // 0..16383
  const int h = gid & (H_DIM - 1);
  const float uu = u[h];
  float hh = 0.f, sum = 0.f, sumsq = 0.f;
  float* p = z + gid;
  constexpr int STRIDE = B_DIM * H_DIM;  // 16384
  constexpr int CH = 32;
  constexpr int NCH = T_DIM / CH;  // 64 chunks
  float va[CH], vb[CH];

#pragma unroll
  for (int c = 0; c < CH; ++c) va[c] = p[(size_t)c * STRIDE];

  for (int i = 0; i < (NCH - 2) / 2; ++i) {  // pairs (0,1)..(60,61)
    const int t0 = i * 2 * CH;
#pragma unroll
    for (int c = 0; c < CH; ++c) vb[c] = p[(size_t)(t0 + CH + c) * STRIDE];
#pragma unroll
    for (int c = 0; c < CH; ++c) {
      hh = fmaxf(va[c] + uu * hh, 0.f);
      va[c] = hh;
      sum += hh;
      sumsq += hh * hh;
    }
#pragma unroll
    for (int c = 0; c < CH; ++c) p[(size_t)(t0 + c) * STRIDE] = va[c];
#pragma unroll
    for (int c = 0; c < CH; ++c) va[c] = p[(size_t)(t0 + 2 * CH + c) * STRIDE];
#pragma unroll
    for (int c = 0; c < CH; ++c) {
      hh = fmaxf(vb[c] + uu * hh, 0.f);
      vb[c] = hh;
      sum += hh;
      sumsq += hh * hh;
    }
#pragma unroll
    for (int c = 0; c < CH; ++c) p[(size_t)(t0 + CH + c) * STRIDE] = vb[c];
  }
  // tail: chunks NCH-2 (in va), NCH-1
  {
    const int t0 = (NCH - 2) * CH;
#pragma unroll
    for (int c = 0; c < CH; ++c) vb[c] = p[(size_t)(t0 + CH + c) * STRIDE];
#pragma unroll
    for (int c = 0; c < CH; ++c) {
      hh = fmaxf(va[c] + uu * hh, 0.f);
      va[c] = hh;
      sum += hh;
      sumsq += hh * hh;
    }
#pragma unroll
    for (int c = 0; c < CH; ++c) p[(size_t)(t0 + c) * STRIDE] = va[c];
#pragma unroll
    for (int c = 0; c < CH; ++c) {
      hh = fmaxf(vb[c] + uu * hh, 0.f);
      vb[c] = hh;
      sum += hh;
      sumsq += hh * hh;
    }
#pragma unroll
    for (int c = 0; c < CH; ++c) p[(size_t)(t0 + CH + c) * STRIDE] = vb[c];
  }
  atomicAdd(&stats[h], sum);
  atomicAdd(&stats[H_DIM + h], sumsq);
}

__global__ __launch_bounds__(1024) void zero_stats(float* __restrict__ stats) {
  stats[threadIdx.x] = 0.f;  // 1024 == 2*H exactly
}

__global__ __launch_bounds__(64) void fill_sentinel(float* __restrict__ out,
                                                    int n) {
  for (int i = threadIdx.x; i < n; i += 64) out[i] = 1.0e6f;
}

// ---------------------------------------------------------------------------
// Convert raw f32 weights (layer 0) to bf16 hi/lo in fragment-swizzled order.
// ---------------------------------------------------------------------------
template <int K>
__global__ __launch_bounds__(256) void convert_w(
    const float* __restrict__ W, unsigned short* __restrict__ Whi,
    unsigned short* __restrict__ Wlo) {
  constexpr int NIT = K / 16;
  int i = blockIdx.x * 256 + threadIdx.x;
  if (i < H_DIM * K) {
    int o = i / K, k = i % K;
    float v = W[i];
    unsigned short h = f2bf(v);
    size_t idx =
        ((size_t)((o >> 5) * NIT + (k >> 4)) * 64 + ((k >> 3) & 1) * 32 +
         (o & 31)) * 8 + (k & 7);
    Whi[idx] = h;
    Wlo[idx] = f2bf(v - bf2f(h));
  }
}

// ---------------------------------------------------------------------------
// Fold BN of previous layer into next layer's weights, emit swizzled bf16:
//   a[i] = gamma[i]*rsqrt(var[i]+eps); c[i] = beta[i] - mean[i]*a[i]
//   Wf[o,i] = Wn[o,i]*a[i];  bf[o] = bn[o] + sum_i Wn[o,i]*c[i]
// ---------------------------------------------------------------------------
__global__ __launch_bounds__(256) void bn_fold(
    const float* __restrict__ stats, const float* __restrict__ gamma,
    const float* __restrict__ beta, const float* __restrict__ Wn,
    const float* __restrict__ bn, unsigned short* __restrict__ Whi,
    unsigned short* __restrict__ Wlo, float* __restrict__ bf) {
  constexpr int NIT = H_DIM / 16;
  const int o = blockIdx.x;
  const int tid = threadIdx.x;
  constexpr float invTB = 1.f / (float)(T_DIM * B_DIM);
  float part = 0.f;
  for (int i = tid; i < H_DIM; i += 256) {
    float mean = stats[i] * invTB;
    float var = stats[H_DIM + i] * invTB - mean * mean;
    float a = gamma[i] * rsqrtf(var + BN_EPS);
    float c = beta[i] - mean * a;
    float w = Wn[(size_t)o * H_DIM + i];
    float wf = w * a;
    unsigned short h = f2bf(wf);
    size_t idx =
        ((size_t)((o >> 5) * NIT + (i >> 4)) * 64 + ((i >> 3) & 1) * 32 +
         (o & 31)) * 8 + (i & 7);
    Whi[idx] = h;
    Wlo[idx] = f2bf(wf - bf2f(h));
    part += w * c;
  }
  __shared__ float red[256];
  red[tid] = part;
  __syncthreads();
  for (int s = 128; s > 0; s >>= 1) {
    if (tid < s) red[tid] += red[tid + s];
    __syncthreads();
  }
  if (tid == 0) bf[o] = bn[o] + red[0];
}

// ---------------------------------------------------------------------------
// Final: out[b,c] = sum_i (s5[T-1,b,i]*a5[i] + c5[i]) * Wout[c,i] + bout[c]
// ---------------------------------------------------------------------------
__global__ __launch_bounds__(64) void final_out(const float* __restrict__ s5,
                                                const float* __restrict__ stats,
                                                const float* __restrict__ gamma,
                                                const float* __restrict__ beta,
                                                const float* __restrict__ Wout,
                                                const float* __restrict__ bout,
                                                float* __restrict__ out) {
  const int b = blockIdx.x / C_DIM, cls = blockIdx.x % C_DIM;
  const int lane = threadIdx.x;
  constexpr float invTB = 1.f / (float)(T_DIM * B_DIM);
  const float* srow =
      s5 + (size_t)(T_DIM - 1) * B_DIM * H_DIM + (size_t)b * H_DIM;
  float part = 0.f;
  for (int i = lane; i < H_DIM; i += 64) {
    float mean = stats[i] * invTB;
    float var = stats[H_DIM + i] * invTB - mean * mean;
    float a = gamma[i] * rsqrtf(var + BN_EPS);
    float c = beta[i] - mean * a;
    part += (srow[i] * a + c) * Wout[(size_t)cls * H_DIM + i];
  }
#pragma unroll
  for (int off = 32; off > 0; off >>= 1) part += __shfl_down(part, off);
  if (lane == 0) out[b * C_DIM + cls] = part + bout[cls];
}

// ---------------------------------------------------------------------------
extern "C" void kernel_launch(void* const* d_in, const int* in_sizes, int n_in,
                              void* d_out, int out_size, void* d_ws,
                              size_t ws_size, hipStream_t stream) {
  const float* x     = (const float*)d_in[0];
  const float* W0    = (const float*)d_in[1];
  const float* b0    = (const float*)d_in[2];
  const float* Wh    = (const float*)d_in[3];
  const float* bh    = (const float*)d_in[4];
  const float* u     = (const float*)d_in[5];
  const float* gamma = (const float*)d_in[6];
  const float* beta  = (const float*)d_in[7];
  const float* Wout  = (const float*)d_in[8];
  const float* bout  = (const float*)d_in[9];
  float* out = (float*)d_out;

  const size_t need = TBH * sizeof(float) +
                      (size_t)H_DIM * H_DIM * 2 * sizeof(unsigned short) +
                      3 * H_DIM * sizeof(float);
  if (ws_size < need) {
    fill_sentinel<<<1, 64, 0, stream>>>(out, out_size);
    return;
  }

  float* ws = (float*)d_ws;
  float* buf = ws;                                     // 128 MB activations
  unsigned short* Whi = (unsigned short*)(ws + TBH);   // 512 KB
  unsigned short* Wlo = Whi + (size_t)H_DIM * H_DIM;   // 512 KB
  float* bf = (float*)(Wlo + (size_t)H_DIM * H_DIM);   // 2 KB
  float* stats = bf + H_DIM;                           // 4 KB

  const int gemm_blocks = TB / ROWS;  // 1024
  const int scan_blocks = (B_DIM * H_DIM) / 64;

  // ---- layer 0: x (K=128) -> buf ----
  convert_w<D_DIM><<<(H_DIM * D_DIM + 255) / 256, 256, 0, stream>>>(W0, Whi,
                                                                    Wlo);
  gemm_mfma<D_DIM><<<gemm_blocks, 512, 0, stream>>>(x, Whi, Wlo, b0, buf);
  zero_stats<<<1, 1024, 0, stream>>>(stats);
  indrnn_scan<<<scan_blocks, 64, 0, stream>>>(buf, u, stats);

  // ---- layers 1..5: in-place buf -> buf ----
  for (int l = 1; l < L_DIM; ++l) {
    bn_fold<<<H_DIM, 256, 0, stream>>>(
        stats, gamma + (size_t)(l - 1) * H_DIM, beta + (size_t)(l - 1) * H_DIM,
        Wh + (size_t)(l - 1) * H_DIM * H_DIM, bh + (size_t)(l - 1) * H_DIM,
        Whi, Wlo, bf);
    gemm_mfma<H_DIM><<<gemm_blocks, 512, 0, stream>>>(buf, Whi, Wlo, bf, buf);
    zero_stats<<<1, 1024, 0, stream>>>(stats);
    indrnn_scan<<<scan_blocks, 64, 0, stream>>>(buf, u + (size_t)l * H_DIM,
                                                stats);
  }

  // ---- final projection (BN of layer 5 applied on the fly) ----
  final_out<<<B_DIM * C_DIM, 64, 0, stream>>>(
      buf, stats, gamma + 5 * (size_t)H_DIM, beta + 5 * (size_t)H_DIM, Wout,
      bout, out);
}